// Round 9
// baseline (442.603 us; speedup 1.0000x reference)
//
#include <hip/hip_runtime.h>

// AttentionPooling: N=262144, DIM=256, H=4, HD=64, B=4096 (batch sorted).
// R14 vs R13 (394 us, best; dispatch fusion won ~17; attn ~120-125 remains).
//   Theory: all five prior main-loop structures consumed global loads directly
//   in the dependent chain (depth-1, 2-4 KB/stream posted ~30% of the time) ->
//   time-averaged in-flight bytes/CU far below BW x latency -> 2.1 TB/s ceiling.
//   R7/R8 (occupancy), R9 (cheaper chain), R11 (reg depth, -occupancy) all left
//   the duty cycle untouched -> neutral. Fix: double-buffered LDS tile staging
//   (T14 async-split): issue tile k+1 loads -> compute tile k FROM LDS
//   (~120cyc) -> ds_write k+1 -> 1 barrier. 16-row tiles, 2x16 KB buffers,
//   32 KB/block -> 4 blocks/CU; 16 KB/block posted ~90% duty = ~64 KB/CU.
//   Compute, red32, Sacc layout, fused vwT epilogue (aliased into tile LDS)
//   carried unchanged from R13 -> clean A/B of load decoupling.
//   launch_bounds(256,3): VGPR cap 170 (no R8-style spill trap); usage ~115.

constexpr int DIM = 256;
constexpr int NH  = 4;
constexpr int HD  = 64;
constexpr float SCL  = 0.125f;   // HD^-0.5
constexpr float EPSV = 1e-8f;

// workspace layout (float offsets)
constexpr int WS_QW   = 0;       // 1024 floats: folded query.key_w
constexpr int WS_QB   = 1024;    // 4 floats
constexpr int WS_OFFS = 1088;    // B+1 ints (4097 ints, ends < 8192 floats)
constexpr int WS_VWT  = 8192;    // 65536 floats: float4[jj=0..63][t=0..255]

// ---- DPP/swizzle reduce: sum over each 32-lane half ----
template<int CTRL>
__device__ __forceinline__ float dpp_ror_add(float v){
  int r = __builtin_amdgcn_update_dpp(0, __float_as_int(v), CTRL, 0xF, 0xF, false);
  return v + __int_as_float(r);
}
__device__ __forceinline__ float red32(float v){
  v = dpp_ror_add<0x121>(v);   // row_ror:1
  v = dpp_ror_add<0x122>(v);   // row_ror:2
  v = dpp_ror_add<0x124>(v);   // row_ror:4
  v = dpp_ror_add<0x128>(v);   // row_ror:8  -> 16-lane row sum
  int r = __builtin_amdgcn_ds_swizzle(__float_as_int(v), 0x401F);  // xor16
  return v + __int_as_float(r);
}

// ---- merged prep: [0,64) vwt transpose, [64,68) qw fold, [68,..) seg offsets ----
__global__ void prep_seg(const float* __restrict__ query,
                         const float* __restrict__ key_w,
                         const float* __restrict__ key_b,
                         const float* __restrict__ value_w,
                         const int* __restrict__ batch32,
                         float* __restrict__ ws,
                         int* __restrict__ offs,
                         int N, int B, int do_vwt){
  const int bid = blockIdx.x, tid = threadIdx.x;
  if (bid < 64){
    if (do_vwt){
      float4 v = *(const float4*)(value_w + (size_t)tid*DIM + 4*bid);  // one-time gather
      ((float4*)(ws + WS_VWT))[bid*256 + tid] = v;                     // coalesced write
    }
  } else if (bid < 68){
    int t = (bid - 64)*256 + tid;     // 0..1023
    int h = t >> 8, j = t & 255;
    float acc = 0.f;
    #pragma unroll 8
    for (int d = 0; d < HD; ++d)
      acc += query[h*HD+d] * key_w[(size_t)(h*HD+d)*DIM + j];
    ws[WS_QW + t] = acc;
    if (j == 0){
      float bb = 0.f;
      for (int d = 0; d < HD; ++d)
        bb += query[h*HD+d] * key_b[h*HD+d];
      ws[WS_QB + h] = bb;
    }
  } else {
    int i = (bid - 68)*256 + tid;
    if (i >= N) return;
    const bool is64 = (batch32[N-1] == 0);   // int64: that int is a high word = 0
    int v  = is64 ? batch32[2*i] : batch32[i];
    int vp = (i == 0) ? -1 : (is64 ? batch32[2*(i-1)] : batch32[i-1]);
    for (int b = vp + 1; b <= v; ++b) offs[b] = i;
    if (i == N-1)
      for (int b = v + 1; b <= B; ++b) offs[b] = N;
  }
}

// ---- main: one block (256 thr) per segment; 16-row LDS tiles, double-buffered.
// Stream = half-wave sigma handles tile-local rows 2s, 2s+1 (8 streams x 2 = 16).
// Epilogue (S_all/Sfin) aliases the tile buffers -> 32 KB LDS total, 4 blocks/CU.
__global__ __launch_bounds__(256, 3)
void attn_tile(const float* __restrict__ x,
               const int* __restrict__ offs,
               const float* __restrict__ ws,
               const float* __restrict__ value_b,
               float* __restrict__ out){
  __shared__ __align__(16) float lds[8192];   // 2 x (16 rows x 256 f) = 32 KB
  __shared__ float sums_all[4][NH];
  __shared__ float invs[NH], wsums[NH];

  const int b   = blockIdx.x;
  const int tid = threadIdx.x;
  const int s = offs[b], e = offs[b+1];
  const int len = e - s;

  const int wave = tid >> 6, lane = tid & 63;
  const int half = lane >> 5, sl = lane & 31;   // half-wave = one stream
  const int sigma = wave * 2 + half;            // stream id 0..7

  // lane-resident qw fragment: cols [4sl..4sl+3] and [128+4sl..128+4sl+3]
  float qwr[NH][8];
  #pragma unroll
  for (int h = 0; h < NH; ++h){
    float4 a = *(const float4*)(ws + WS_QW + h*DIM + 4*sl);
    float4 c = *(const float4*)(ws + WS_QW + h*DIM + 128 + 4*sl);
    qwr[h][0]=a.x; qwr[h][1]=a.y; qwr[h][2]=a.z; qwr[h][3]=a.w;
    qwr[h][4]=c.x; qwr[h][5]=c.y; qwr[h][6]=c.z; qwr[h][7]=c.w;
  }
  float qb[NH];
  #pragma unroll
  for (int h = 0; h < NH; ++h) qb[h] = ws[WS_QB + h];

  float Sacc[NH][8];
  #pragma unroll
  for (int h = 0; h < NH; ++h)
    #pragma unroll
    for (int c = 0; c < 8; ++c) Sacc[h][c] = 0.f;
  float se[NH] = {0.f, 0.f, 0.f, 0.f};

  const float4* xr4 = (const float4*)x;   // one row = 64 float4
  float4* lbuf4 = (float4*)lds;

  if (len > 0){
    const int ntiles = (len + 15) >> 4;
    const long gmax = (long)e * 64 - 1;           // clamp: stay in-bounds

    // stage tile 0: thread stages f4 slots {tid + j*256} (linear in global too)
    {
      float4 r0[4];
      #pragma unroll
      for (int j = 0; j < 4; ++j){
        long gi = (long)s*64 + tid + j*256;
        gi = gi < gmax ? gi : gmax;
        r0[j] = xr4[gi];
      }
      #pragma unroll
      for (int j = 0; j < 4; ++j) lbuf4[tid + j*256] = r0[j];
    }
    __syncthreads();

    int cur = 0;
    for (int k = 0; k < ntiles; ++k){
      // issue loads for tile k+1 FIRST (hide HBM latency under compute)
      float4 rn[4];
      const bool more = (k + 1 < ntiles);
      if (more){
        const long tb = (long)(s + (k+1)*16) * 64;
        #pragma unroll
        for (int j = 0; j < 4; ++j){
          long gi = tb + tid + j*256;
          gi = gi < gmax ? gi : gmax;
          rn[j] = xr4[gi];
        }
      }

      // compute tile k from LDS buf[cur]: one chain per stream (2 nodes)
      const float* base = lds + cur*4096;
      const int gr0 = s + k*16 + 2*sigma;
      float4 a0 = *(const float4*)(base + (2*sigma)*256 + 4*sl);
      float4 b0 = *(const float4*)(base + (2*sigma)*256 + 128 + 4*sl);
      float4 a1 = *(const float4*)(base + (2*sigma+1)*256 + 4*sl);
      float4 b1 = *(const float4*)(base + (2*sigma+1)*256 + 128 + 4*sl);

      float xv0[8] = {a0.x,a0.y,a0.z,a0.w,b0.x,b0.y,b0.z,b0.w};
      float xv1[8] = {a1.x,a1.y,a1.z,a1.w,b1.x,b1.y,b1.z,b1.w};

      float p0[NH], p1[NH];
      #pragma unroll
      for (int h = 0; h < NH; ++h){
        float s0 = 0.f, s1 = 0.f;
        #pragma unroll
        for (int c = 0; c < 8; ++c){ s0 += qwr[h][c]*xv0[c]; s1 += qwr[h][c]*xv1[c]; }
        p0[h] = s0; p1[h] = s1;
      }
      #pragma unroll
      for (int h = 0; h < NH; ++h){
        p0[h] = red32(p0[h]);
        p1[h] = red32(p1[h]);
      }
      const float g0 = (gr0     < e) ? 1.f : 0.f;
      const float g1 = (gr0 + 1 < e) ? 1.f : 0.f;
      #pragma unroll
      for (int h = 0; h < NH; ++h){
        float e0 = __expf((p0[h] + qb[h]) * SCL) * g0;
        float e1 = __expf((p1[h] + qb[h]) * SCL) * g1;
        se[h] += e0 + e1;
        #pragma unroll
        for (int c = 0; c < 8; ++c)
          Sacc[h][c] += e0*xv0[c] + e1*xv1[c];
      }

      // write tile k+1 into the other buffer (safe: k-1 readers done at last barrier)
      if (more){
        #pragma unroll
        for (int j = 0; j < 4; ++j) lbuf4[(cur^1)*1024 + tid + j*256] = rn[j];
      }
      __syncthreads();
      cur ^= 1;
    }
  }
  __syncthreads();   // all compute done; tile buffers reusable as S_all/Sfin

  // combine the two streams of each wave (same columns, different rows)
  #pragma unroll
  for (int h = 0; h < NH; ++h){
    se[h] += __shfl_xor(se[h], 32, 64);
    #pragma unroll
    for (int c = 0; c < 8; ++c) Sacc[h][c] += __shfl_xor(Sacc[h][c], 32, 64);
  }
  // S_all[wave] = lds + wave*1024; Sfin = lds + 4096
  float* S_all = lds;
  float* Sfin  = lds + 4096;
  if (half == 0){
    #pragma unroll
    for (int h = 0; h < NH; ++h){
      float4 lo = make_float4(Sacc[h][0], Sacc[h][1], Sacc[h][2], Sacc[h][3]);
      float4 hi = make_float4(Sacc[h][4], Sacc[h][5], Sacc[h][6], Sacc[h][7]);
      *(float4*)&S_all[wave*1024 + h*DIM + 4*sl]       = lo;
      *(float4*)&S_all[wave*1024 + h*DIM + 128 + 4*sl] = hi;
    }
    if (sl == 0){
      #pragma unroll
      for (int h = 0; h < NH; ++h) sums_all[wave][h] = se[h];
    }
  }
  __syncthreads();

  // reduce 4 wave-copies into Sfin; totals -> invs/wsums
  #pragma unroll
  for (int k = 0; k < 4; ++k){
    const int idx = tid + k*256;
    Sfin[idx] = S_all[0*1024 + idx] + S_all[1*1024 + idx]
              + S_all[2*1024 + idx] + S_all[3*1024 + idx];
  }
  if (tid < NH){
    float tot = sums_all[0][tid] + sums_all[1][tid]
              + sums_all[2][tid] + sums_all[3][tid];
    float inv = 1.f / (tot + EPSV);
    invs[tid]  = inv;
    wsums[tid] = tot * inv;
  }
  __syncthreads();

  // fused COALESCED epilogue: thread t owns out[b,t]; vwt4[jj*256+t] is
  // 1 KB/instr coalesced and L2-resident; Sfin reads are wave-broadcast.
  const int t = tid, h = t >> 6;                  // h wave-uniform
  const float4* vwt4 = (const float4*)(ws + WS_VWT);
  const float4* sp   = (const float4*)&Sfin[h*256];
  float acc = 0.f;
  #pragma unroll 8
  for (int jj = 0; jj < 64; ++jj){
    const float4 w4 = vwt4[jj*256 + t];
    const float4 s4 = sp[jj];
    acc += w4.x*s4.x + w4.y*s4.y + w4.z*s4.z + w4.w*s4.w;
  }
  out[(size_t)b*256 + t] = acc * invs[h] + wsums[h] * value_b[t];
}

// ---- minimal fused fallback (value_w row gather) for tiny workspace ----
__global__ __launch_bounds__(512, 4)
void attn_pool_fused(const float* __restrict__ x,
                     const int* __restrict__ offs,
                     const float* __restrict__ ws,
                     const float* __restrict__ value_w,
                     const float* __restrict__ value_b,
                     float* __restrict__ out){
  __shared__ __align__(16) float lds[8192 + 32 + 1024 + 512 + 8];
  float* S_all    = lds;          // [8][4][256]
  float* sums_all = lds + 8192;   // [8][4]

  const int b   = blockIdx.x;
  const int tid = threadIdx.x;
  const int seg_start = offs[b];
  const int seg_end   = offs[b+1];

  const int wave = tid >> 6, lane = tid & 63;
  const int half = lane >> 5, sl = lane & 31;
  const int sigma = wave * 2 + half;

  float qwr[NH][8];
  #pragma unroll
  for (int h = 0; h < NH; ++h){
    float4 a = *(const float4*)(ws + WS_QW + h*DIM + 4*sl);
    float4 c = *(const float4*)(ws + WS_QW + h*DIM + 128 + 4*sl);
    qwr[h][0]=a.x; qwr[h][1]=a.y; qwr[h][2]=a.z; qwr[h][3]=a.w;
    qwr[h][4]=c.x; qwr[h][5]=c.y; qwr[h][6]=c.z; qwr[h][7]=c.w;
  }
  float qb[NH];
  #pragma unroll
  for (int h = 0; h < NH; ++h) qb[h] = ws[WS_QB + h];

  float Sacc[NH][8];
  #pragma unroll
  for (int h = 0; h < NH; ++h)
    #pragma unroll
    for (int c = 0; c < 8; ++c) Sacc[h][c] = 0.f;
  float se[NH] = {0.f, 0.f, 0.f, 0.f};

  const float4* xr4 = (const float4*)x;
  const float4 Z = make_float4(0.f,0.f,0.f,0.f);

  int n0 = seg_start + sigma*2;
  bool v0 = n0 < seg_end;
  bool v1 = n0 + 1 < seg_end;
  float4 a0=Z, b0=Z, a1=Z, b1=Z;
  if (v0){ a0 = xr4[(size_t)n0*64 + sl];     b0 = xr4[(size_t)n0*64 + 32 + sl]; }
  if (v1){ a1 = xr4[(size_t)(n0+1)*64 + sl]; b1 = xr4[(size_t)(n0+1)*64 + 32 + sl]; }

  while (v0){
    const int nn = n0 + 32;
    const bool w0 = nn < seg_end;
    const bool w1 = nn + 1 < seg_end;
    float4 c0=Z, d0=Z, c1=Z, d1=Z;
    if (w0){ c0 = xr4[(size_t)nn*64 + sl];     d0 = xr4[(size_t)nn*64 + 32 + sl]; }
    if (w1){ c1 = xr4[(size_t)(nn+1)*64 + sl]; d1 = xr4[(size_t)(nn+1)*64 + 32 + sl]; }

    float xv0[8] = {a0.x,a0.y,a0.z,a0.w,b0.x,b0.y,b0.z,b0.w};
    float xv1[8] = {a1.x,a1.y,a1.z,a1.w,b1.x,b1.y,b1.z,b1.w};

    float p0[NH], p1[NH];
    #pragma unroll
    for (int h = 0; h < NH; ++h){
      float s0 = 0.f, s1 = 0.f;
      #pragma unroll
      for (int c = 0; c < 8; ++c){ s0 += qwr[h][c]*xv0[c]; s1 += qwr[h][c]*xv1[c]; }
      p0[h] = s0; p1[h] = s1;
    }
    #pragma unroll
    for (int m = 1; m < 32; m <<= 1){
      #pragma unroll
      for (int h = 0; h < NH; ++h){
        p0[h] += __shfl_xor(p0[h], m, 64);
        p1[h] += __shfl_xor(p1[h], m, 64);
      }
    }
    const float g1 = v1 ? 1.f : 0.f;
    #pragma unroll
    for (int h = 0; h < NH; ++h){
      float e0 = __expf((p0[h] + qb[h]) * SCL);
      float e1 = __expf((p1[h] + qb[h]) * SCL) * g1;
      se[h] += e0 + e1;
      #pragma unroll
      for (int c = 0; c < 8; ++c)
        Sacc[h][c] += e0*xv0[c] + e1*xv1[c];
    }
    n0 = nn; v0 = w0; v1 = w1;
    a0 = c0; b0 = d0; a1 = c1; b1 = d1;
  }

  #pragma unroll
  for (int h = 0; h < NH; ++h){
    se[h] += __shfl_xor(se[h], 32, 64);
    #pragma unroll
    for (int c = 0; c < 8; ++c) Sacc[h][c] += __shfl_xor(Sacc[h][c], 32, 64);
  }
  if (half == 0){
    #pragma unroll
    for (int h = 0; h < NH; ++h){
      float4 lo = make_float4(Sacc[h][0], Sacc[h][1], Sacc[h][2], Sacc[h][3]);
      float4 hi = make_float4(Sacc[h][4], Sacc[h][5], Sacc[h][6], Sacc[h][7]);
      *(float4*)&S_all[wave*1024 + h*DIM + 4*sl]       = lo;
      *(float4*)&S_all[wave*1024 + h*DIM + 128 + 4*sl] = hi;
    }
    if (sl == 0){
      #pragma unroll
      for (int h = 0; h < NH; ++h) sums_all[wave*4 + h] = se[h];
    }
  }
  __syncthreads();

  float* Sfin  = lds + 8224;
  float* invs  = lds + 9760;
  float* wsums = invs + 4;
  #pragma unroll
  for (int k = 0; k < 2; ++k){
    const int idx = tid + k*512;
    float sv = 0.f;
    #pragma unroll
    for (int w = 0; w < 8; ++w) sv += S_all[w*1024 + idx];
    Sfin[idx] = sv;
  }
  if (tid < NH){
    float tot = 0.f;
    #pragma unroll
    for (int w = 0; w < 8; ++w) tot += sums_all[w*4 + tid];
    float inv = 1.f / (tot + EPSV);
    invs[tid] = inv; wsums[tid] = tot * inv;
  }
  __syncthreads();

  float* ep2 = lds + 9248;
  const int t = tid & 255, part = tid >> 8;
  const int h2 = t >> 6;
  const float4* vrow = (const float4*)(value_w + (size_t)t * DIM) + part*32;
  const float4* sp   = (const float4*)&Sfin[h2*256] + part*32;
  float acc = 0.f;
  #pragma unroll
  for (int q = 0; q < 32; ++q){
    float4 r = vrow[q];
    float4 sv = sp[q];
    acc += r.x*sv.x + r.y*sv.y + r.z*sv.z + r.w*sv.w;
  }
  ep2[part*256 + t] = acc;
  __syncthreads();
  if (part == 0)
    out[(size_t)b * DIM + t] = (ep2[t] + ep2[256 + t]) * invs[h2] + wsums[h2] * value_b[t];
}

extern "C" void kernel_launch(void* const* d_in, const int* in_sizes, int n_in,
                              void* d_out, int out_size, void* d_ws, size_t ws_size,
                              hipStream_t stream){
  const float* x       = (const float*)d_in[0];
  const int*   batch   = (const int*)d_in[1];
  const float* query   = (const float*)d_in[2];
  const float* key_w   = (const float*)d_in[3];
  const float* key_b   = (const float*)d_in[4];
  const float* value_w = (const float*)d_in[5];
  const float* value_b = (const float*)d_in[6];
  float* ws  = (float*)d_ws;
  float* out = (float*)d_out;

  const int N = in_sizes[1];        // 262144
  const int B = out_size / DIM;     // 4096

  int* offs = (int*)(ws + WS_OFFS);

  const size_t need_vwt = ((size_t)WS_VWT + 65536) * sizeof(float);
  const int do_vwt = (ws_size >= need_vwt) ? 1 : 0;

  const int seg_blocks = (N + 255) / 256;
  prep_seg<<<68 + seg_blocks, 256, 0, stream>>>(query, key_w, key_b, value_w,
                                                batch, ws, offs, N, B, do_vwt);
  if (do_vwt)
    attn_tile<<<B, 256, 0, stream>>>(x, offs, ws, value_b, out);
  else
    attn_pool_fused<<<B, 512, 0, stream>>>(x, offs, ws, value_w, value_b, out);
}

// Round 10
// 396.421 us; speedup vs baseline: 1.1165x; 1.1165x over previous
//
#include <hip/hip_runtime.h>

// AttentionPooling: N=262144, DIM=256, H=4, HD=64, B=4096 (batch sorted).
// R15 vs R14 (443 us FAILED -- but CONFOUNDED: VGPR_Count=60 + WRITE_SIZE=184MB
//            = allocator pinned regs low and spilled the 16 staged float4s to
//            scratch every tile (R7 pathology). Load-decoupling never tested.)
//   Fix: __builtin_amdgcn_global_load_lds width=16 (CDNA cp.async analog):
//        async global->LDS DMA, ZERO staging registers. Our linear staging is
//        exactly the HW pattern: LDS dest = wave-uniform base (wave*64+j*256
//        f4) + lane*16B; global src per-lane (tid+j*256). Per tile: issue 4
//        gll for tile k+1 -> compute tile k from LDS -> __syncthreads (its
//        implicit vmcnt drain lands k+1, which flew under the ~600cyc compute)
//        -> flip. VGPR back to R13 levels under launch_bounds(256,4) (proven).
//   Everything else identical to R13 (best 394 us): prep_seg merged dispatch,
//   red32 DPP reduce, fused coalesced vwT epilogue aliasing the tile LDS.

constexpr int DIM = 256;
constexpr int NH  = 4;
constexpr int HD  = 64;
constexpr float SCL  = 0.125f;   // HD^-0.5
constexpr float EPSV = 1e-8f;

// workspace layout (float offsets)
constexpr int WS_QW   = 0;       // 1024 floats: folded query.key_w
constexpr int WS_QB   = 1024;    // 4 floats
constexpr int WS_OFFS = 1088;    // B+1 ints (4097 ints, ends < 8192 floats)
constexpr int WS_VWT  = 8192;    // 65536 floats: float4[jj=0..63][t=0..255]

// ---- async global->LDS 16B (no VGPR roundtrip) ----
__device__ __forceinline__ void gll16(const float4* g, float4* l){
  __builtin_amdgcn_global_load_lds(
      (const __attribute__((address_space(1))) void*)g,
      (__attribute__((address_space(3))) void*)l, 16, 0, 0);
}

// ---- DPP/swizzle reduce: sum over each 32-lane half ----
template<int CTRL>
__device__ __forceinline__ float dpp_ror_add(float v){
  int r = __builtin_amdgcn_update_dpp(0, __float_as_int(v), CTRL, 0xF, 0xF, false);
  return v + __int_as_float(r);
}
__device__ __forceinline__ float red32(float v){
  v = dpp_ror_add<0x121>(v);   // row_ror:1
  v = dpp_ror_add<0x122>(v);   // row_ror:2
  v = dpp_ror_add<0x124>(v);   // row_ror:4
  v = dpp_ror_add<0x128>(v);   // row_ror:8  -> 16-lane row sum
  int r = __builtin_amdgcn_ds_swizzle(__float_as_int(v), 0x401F);  // xor16
  return v + __int_as_float(r);
}

// ---- merged prep: [0,64) vwt transpose, [64,68) qw fold, [68,..) seg offsets ----
__global__ void prep_seg(const float* __restrict__ query,
                         const float* __restrict__ key_w,
                         const float* __restrict__ key_b,
                         const float* __restrict__ value_w,
                         const int* __restrict__ batch32,
                         float* __restrict__ ws,
                         int* __restrict__ offs,
                         int N, int B, int do_vwt){
  const int bid = blockIdx.x, tid = threadIdx.x;
  if (bid < 64){
    if (do_vwt){
      float4 v = *(const float4*)(value_w + (size_t)tid*DIM + 4*bid);  // one-time gather
      ((float4*)(ws + WS_VWT))[bid*256 + tid] = v;                     // coalesced write
    }
  } else if (bid < 68){
    int t = (bid - 64)*256 + tid;     // 0..1023
    int h = t >> 8, j = t & 255;
    float acc = 0.f;
    #pragma unroll 8
    for (int d = 0; d < HD; ++d)
      acc += query[h*HD+d] * key_w[(size_t)(h*HD+d)*DIM + j];
    ws[WS_QW + t] = acc;
    if (j == 0){
      float bb = 0.f;
      for (int d = 0; d < HD; ++d)
        bb += query[h*HD+d] * key_b[h*HD+d];
      ws[WS_QB + h] = bb;
    }
  } else {
    int i = (bid - 68)*256 + tid;
    if (i >= N) return;
    const bool is64 = (batch32[N-1] == 0);   // int64: that int is a high word = 0
    int v  = is64 ? batch32[2*i] : batch32[i];
    int vp = (i == 0) ? -1 : (is64 ? batch32[2*(i-1)] : batch32[i-1]);
    for (int b = vp + 1; b <= v; ++b) offs[b] = i;
    if (i == N-1)
      for (int b = v + 1; b <= B; ++b) offs[b] = N;
  }
}

// ---- main: one block (256 thr) per segment; 16-row LDS tiles double-buffered
// via async global_load_lds (no staging registers). Stream = half-wave sigma
// handles tile rows 2s,2s+1. Epilogue aliases the tile LDS (32 KB total).
__global__ __launch_bounds__(256, 4)
void attn_gll(const float* __restrict__ x,
              const int* __restrict__ offs,
              const float* __restrict__ ws,
              const float* __restrict__ value_b,
              float* __restrict__ out){
  __shared__ __align__(16) float lds[8192];   // 2 x (16 rows x 256 f) = 32 KB
  __shared__ float sums_all[4][NH];
  __shared__ float invs[NH], wsums[NH];

  const int b   = blockIdx.x;
  const int tid = threadIdx.x;
  const int s = offs[b], e = offs[b+1];
  const int len = e - s;

  const int wave = tid >> 6, lane = tid & 63;
  const int half = lane >> 5, sl = lane & 31;   // half-wave = one stream
  const int sigma = wave * 2 + half;            // stream id 0..7

  // lane-resident qw fragment: cols [4sl..4sl+3] and [128+4sl..128+4sl+3]
  float qwr[NH][8];
  #pragma unroll
  for (int h = 0; h < NH; ++h){
    float4 a = *(const float4*)(ws + WS_QW + h*DIM + 4*sl);
    float4 c = *(const float4*)(ws + WS_QW + h*DIM + 128 + 4*sl);
    qwr[h][0]=a.x; qwr[h][1]=a.y; qwr[h][2]=a.z; qwr[h][3]=a.w;
    qwr[h][4]=c.x; qwr[h][5]=c.y; qwr[h][6]=c.z; qwr[h][7]=c.w;
  }
  float qb[NH];
  #pragma unroll
  for (int h = 0; h < NH; ++h) qb[h] = ws[WS_QB + h];

  float Sacc[NH][8];
  #pragma unroll
  for (int h = 0; h < NH; ++h)
    #pragma unroll
    for (int c = 0; c < 8; ++c) Sacc[h][c] = 0.f;
  float se[NH] = {0.f, 0.f, 0.f, 0.f};

  const float4* xr4 = (const float4*)x;   // one row = 64 float4
  float4* lbuf4 = (float4*)lds;

  if (len > 0){
    const int ntiles = (len + 15) >> 4;
    const long gmax = (long)e * 64 - 1;          // clamp: stay within segment

    // issue tile 0 async: lds slot (wave*64 + j*256) + lane*16B <- per-lane gsrc
    {
      const long tb = (long)s * 64;
      #pragma unroll
      for (int j = 0; j < 4; ++j){
        long gi = tb + tid + j*256;
        gi = gi < gmax ? gi : gmax;
        gll16(xr4 + gi, lbuf4 + wave*64 + j*256);
      }
    }
    __syncthreads();    // implicit vmcnt(0): tile 0 landed

    int cur = 0;
    for (int k = 0; k < ntiles; ++k){
      // issue async loads for tile k+1 into the other buffer
      if (k + 1 < ntiles){
        const long tb = (long)(s + (k+1)*16) * 64;
        #pragma unroll
        for (int j = 0; j < 4; ++j){
          long gi = tb + tid + j*256;
          gi = gi < gmax ? gi : gmax;
          gll16(xr4 + gi, lbuf4 + (cur^1)*1024 + wave*64 + j*256);
        }
      }

      // compute tile k from LDS buf[cur]: one chain per stream (2 nodes)
      const float* base = lds + cur*4096;
      const int gr0 = s + k*16 + 2*sigma;
      float4 a0 = *(const float4*)(base + (2*sigma)*256 + 4*sl);
      float4 b0 = *(const float4*)(base + (2*sigma)*256 + 128 + 4*sl);
      float4 a1 = *(const float4*)(base + (2*sigma+1)*256 + 4*sl);
      float4 b1 = *(const float4*)(base + (2*sigma+1)*256 + 128 + 4*sl);

      float xv0[8] = {a0.x,a0.y,a0.z,a0.w,b0.x,b0.y,b0.z,b0.w};
      float xv1[8] = {a1.x,a1.y,a1.z,a1.w,b1.x,b1.y,b1.z,b1.w};

      float p0[NH], p1[NH];
      #pragma unroll
      for (int h = 0; h < NH; ++h){
        float s0 = 0.f, s1 = 0.f;
        #pragma unroll
        for (int c = 0; c < 8; ++c){ s0 += qwr[h][c]*xv0[c]; s1 += qwr[h][c]*xv1[c]; }
        p0[h] = s0; p1[h] = s1;
      }
      #pragma unroll
      for (int h = 0; h < NH; ++h){
        p0[h] = red32(p0[h]);
        p1[h] = red32(p1[h]);
      }
      const float g0 = (gr0     < e) ? 1.f : 0.f;
      const float g1 = (gr0 + 1 < e) ? 1.f : 0.f;
      #pragma unroll
      for (int h = 0; h < NH; ++h){
        float e0 = __expf((p0[h] + qb[h]) * SCL) * g0;
        float e1 = __expf((p1[h] + qb[h]) * SCL) * g1;
        se[h] += e0 + e1;
        #pragma unroll
        for (int c = 0; c < 8; ++c)
          Sacc[h][c] += e0*xv0[c] + e1*xv1[c];
      }

      __syncthreads();   // drains vmcnt: tile k+1 ready; buf[cur] readers done
      cur ^= 1;
    }
  }
  __syncthreads();   // tile buffers reusable as S_all/Sfin

  // combine the two streams of each wave (same columns, different rows)
  #pragma unroll
  for (int h = 0; h < NH; ++h){
    se[h] += __shfl_xor(se[h], 32, 64);
    #pragma unroll
    for (int c = 0; c < 8; ++c) Sacc[h][c] += __shfl_xor(Sacc[h][c], 32, 64);
  }
  float* S_all = lds;          // [4][1024]
  float* Sfin  = lds + 4096;   // [1024]
  if (half == 0){
    #pragma unroll
    for (int h = 0; h < NH; ++h){
      float4 lo = make_float4(Sacc[h][0], Sacc[h][1], Sacc[h][2], Sacc[h][3]);
      float4 hi = make_float4(Sacc[h][4], Sacc[h][5], Sacc[h][6], Sacc[h][7]);
      *(float4*)&S_all[wave*1024 + h*DIM + 4*sl]       = lo;
      *(float4*)&S_all[wave*1024 + h*DIM + 128 + 4*sl] = hi;
    }
    if (sl == 0){
      #pragma unroll
      for (int h = 0; h < NH; ++h) sums_all[wave][h] = se[h];
    }
  }
  __syncthreads();

  // reduce 4 wave-copies into Sfin; totals -> invs/wsums
  #pragma unroll
  for (int k = 0; k < 4; ++k){
    const int idx = tid + k*256;
    Sfin[idx] = S_all[0*1024 + idx] + S_all[1*1024 + idx]
              + S_all[2*1024 + idx] + S_all[3*1024 + idx];
  }
  if (tid < NH){
    float tot = sums_all[0][tid] + sums_all[1][tid]
              + sums_all[2][tid] + sums_all[3][tid];
    float inv = 1.f / (tot + EPSV);
    invs[tid]  = inv;
    wsums[tid] = tot * inv;
  }
  __syncthreads();

  // fused COALESCED epilogue: thread t owns out[b,t]; vwt4[jj*256+t] is
  // 1 KB/instr coalesced and L2-resident; Sfin reads are wave-broadcast.
  const int t = tid, h = t >> 6;                  // h wave-uniform
  const float4* vwt4 = (const float4*)(ws + WS_VWT);
  const float4* sp   = (const float4*)&Sfin[h*256];
  float acc = 0.f;
  #pragma unroll 8
  for (int jj = 0; jj < 64; ++jj){
    const float4 w4 = vwt4[jj*256 + t];
    const float4 s4 = sp[jj];
    acc += w4.x*s4.x + w4.y*s4.y + w4.z*s4.z + w4.w*s4.w;
  }
  out[(size_t)b*256 + t] = acc * invs[h] + wsums[h] * value_b[t];
}

// ---- minimal fused fallback (value_w row gather) for tiny workspace ----
__global__ __launch_bounds__(512, 4)
void attn_pool_fused(const float* __restrict__ x,
                     const int* __restrict__ offs,
                     const float* __restrict__ ws,
                     const float* __restrict__ value_w,
                     const float* __restrict__ value_b,
                     float* __restrict__ out){
  __shared__ __align__(16) float lds[8192 + 32 + 1024 + 512 + 8];
  float* S_all    = lds;          // [8][4][256]
  float* sums_all = lds + 8192;   // [8][4]

  const int b   = blockIdx.x;
  const int tid = threadIdx.x;
  const int seg_start = offs[b];
  const int seg_end   = offs[b+1];

  const int wave = tid >> 6, lane = tid & 63;
  const int half = lane >> 5, sl = lane & 31;
  const int sigma = wave * 2 + half;

  float qwr[NH][8];
  #pragma unroll
  for (int h = 0; h < NH; ++h){
    float4 a = *(const float4*)(ws + WS_QW + h*DIM + 4*sl);
    float4 c = *(const float4*)(ws + WS_QW + h*DIM + 128 + 4*sl);
    qwr[h][0]=a.x; qwr[h][1]=a.y; qwr[h][2]=a.z; qwr[h][3]=a.w;
    qwr[h][4]=c.x; qwr[h][5]=c.y; qwr[h][6]=c.z; qwr[h][7]=c.w;
  }
  float qb[NH];
  #pragma unroll
  for (int h = 0; h < NH; ++h) qb[h] = ws[WS_QB + h];

  float Sacc[NH][8];
  #pragma unroll
  for (int h = 0; h < NH; ++h)
    #pragma unroll
    for (int c = 0; c < 8; ++c) Sacc[h][c] = 0.f;
  float se[NH] = {0.f, 0.f, 0.f, 0.f};

  const float4* xr4 = (const float4*)x;
  const float4 Z = make_float4(0.f,0.f,0.f,0.f);

  int n0 = seg_start + sigma*2;
  bool v0 = n0 < seg_end;
  bool v1 = n0 + 1 < seg_end;
  float4 a0=Z, b0=Z, a1=Z, b1=Z;
  if (v0){ a0 = xr4[(size_t)n0*64 + sl];     b0 = xr4[(size_t)n0*64 + 32 + sl]; }
  if (v1){ a1 = xr4[(size_t)(n0+1)*64 + sl]; b1 = xr4[(size_t)(n0+1)*64 + 32 + sl]; }

  while (v0){
    const int nn = n0 + 32;
    const bool w0 = nn < seg_end;
    const bool w1 = nn + 1 < seg_end;
    float4 c0=Z, d0=Z, c1=Z, d1=Z;
    if (w0){ c0 = xr4[(size_t)nn*64 + sl];     d0 = xr4[(size_t)nn*64 + 32 + sl]; }
    if (w1){ c1 = xr4[(size_t)(nn+1)*64 + sl]; d1 = xr4[(size_t)(nn+1)*64 + 32 + sl]; }

    float xv0[8] = {a0.x,a0.y,a0.z,a0.w,b0.x,b0.y,b0.z,b0.w};
    float xv1[8] = {a1.x,a1.y,a1.z,a1.w,b1.x,b1.y,b1.z,b1.w};

    float p0[NH], p1[NH];
    #pragma unroll
    for (int h = 0; h < NH; ++h){
      float s0 = 0.f, s1 = 0.f;
      #pragma unroll
      for (int c = 0; c < 8; ++c){ s0 += qwr[h][c]*xv0[c]; s1 += qwr[h][c]*xv1[c]; }
      p0[h] = s0; p1[h] = s1;
    }
    #pragma unroll
    for (int m = 1; m < 32; m <<= 1){
      #pragma unroll
      for (int h = 0; h < NH; ++h){
        p0[h] += __shfl_xor(p0[h], m, 64);
        p1[h] += __shfl_xor(p1[h], m, 64);
      }
    }
    const float g1 = v1 ? 1.f : 0.f;
    #pragma unroll
    for (int h = 0; h < NH; ++h){
      float e0 = __expf((p0[h] + qb[h]) * SCL);
      float e1 = __expf((p1[h] + qb[h]) * SCL) * g1;
      se[h] += e0 + e1;
      #pragma unroll
      for (int c = 0; c < 8; ++c)
        Sacc[h][c] += e0*xv0[c] + e1*xv1[c];
    }
    n0 = nn; v0 = w0; v1 = w1;
    a0 = c0; b0 = d0; a1 = c1; b1 = d1;
  }

  #pragma unroll
  for (int h = 0; h < NH; ++h){
    se[h] += __shfl_xor(se[h], 32, 64);
    #pragma unroll
    for (int c = 0; c < 8; ++c) Sacc[h][c] += __shfl_xor(Sacc[h][c], 32, 64);
  }
  if (half == 0){
    #pragma unroll
    for (int h = 0; h < NH; ++h){
      float4 lo = make_float4(Sacc[h][0], Sacc[h][1], Sacc[h][2], Sacc[h][3]);
      float4 hi = make_float4(Sacc[h][4], Sacc[h][5], Sacc[h][6], Sacc[h][7]);
      *(float4*)&S_all[wave*1024 + h*DIM + 4*sl]       = lo;
      *(float4*)&S_all[wave*1024 + h*DIM + 128 + 4*sl] = hi;
    }
    if (sl == 0){
      #pragma unroll
      for (int h = 0; h < NH; ++h) sums_all[wave*4 + h] = se[h];
    }
  }
  __syncthreads();

  float* Sfin  = lds + 8224;
  float* invs  = lds + 9760;
  float* wsums = invs + 4;
  #pragma unroll
  for (int k = 0; k < 2; ++k){
    const int idx = tid + k*512;
    float sv = 0.f;
    #pragma unroll
    for (int w = 0; w < 8; ++w) sv += S_all[w*1024 + idx];
    Sfin[idx] = sv;
  }
  if (tid < NH){
    float tot = 0.f;
    #pragma unroll
    for (int w = 0; w < 8; ++w) tot += sums_all[w*4 + tid];
    float inv = 1.f / (tot + EPSV);
    invs[tid] = inv; wsums[tid] = tot * inv;
  }
  __syncthreads();

  float* ep2 = lds + 9248;
  const int t = tid & 255, part = tid >> 8;
  const int h2 = t >> 6;
  const float4* vrow = (const float4*)(value_w + (size_t)t * DIM) + part*32;
  const float4* sp   = (const float4*)&Sfin[h2*256] + part*32;
  float acc = 0.f;
  #pragma unroll
  for (int q = 0; q < 32; ++q){
    float4 r = vrow[q];
    float4 sv = sp[q];
    acc += r.x*sv.x + r.y*sv.y + r.z*sv.z + r.w*sv.w;
  }
  ep2[part*256 + t] = acc;
  __syncthreads();
  if (part == 0)
    out[(size_t)b * DIM + t] = (ep2[t] + ep2[256 + t]) * invs[h2] + wsums[h2] * value_b[t];
}

extern "C" void kernel_launch(void* const* d_in, const int* in_sizes, int n_in,
                              void* d_out, int out_size, void* d_ws, size_t ws_size,
                              hipStream_t stream){
  const float* x       = (const float*)d_in[0];
  const int*   batch   = (const int*)d_in[1];
  const float* query   = (const float*)d_in[2];
  const float* key_w   = (const float*)d_in[3];
  const float* key_b   = (const float*)d_in[4];
  const float* value_w = (const float*)d_in[5];
  const float* value_b = (const float*)d_in[6];
  float* ws  = (float*)d_ws;
  float* out = (float*)d_out;

  const int N = in_sizes[1];        // 262144
  const int B = out_size / DIM;     // 4096

  int* offs = (int*)(ws + WS_OFFS);

  const size_t need_vwt = ((size_t)WS_VWT + 65536) * sizeof(float);
  const int do_vwt = (ws_size >= need_vwt) ? 1 : 0;

  const int seg_blocks = (N + 255) / 256;
  prep_seg<<<68 + seg_blocks, 256, 0, stream>>>(query, key_w, key_b, value_w,
                                                batch, ws, offs, N, B, do_vwt);
  if (do_vwt)
    attn_gll<<<B, 256, 0, stream>>>(x, offs, ws, value_b, out);
  else
    attn_pool_fused<<<B, 512, 0, stream>>>(x, offs, ws, value_w, value_b, out);
}